// Round 8
// baseline (263.633 us; speedup 1.0000x reference)
//
#include <hip/hip_runtime.h>
#include <hip/hip_bf16.h>

// Problem: B=4, S=4096, D=256 single-head causal attention, fp32 in/out.
// ws: Qb bf16 [4][4096][256] @0 (8MB)
//     KV @8MB: per (batch, kv-tile t<64) 64KB block:
//        [0..32K):  K swizzled image, byte (r*512 + 2*d) ^ ((r&7)<<4)
//        [32K..64K):V in MFMA-FRAGMENT ORDER: fragment (n=d>>4, ks=s_t>>5) is a
//                   contiguous 1KB burst: byte 32768 + (ks*16+n)*1024 + lane*16,
//                   lane = ((s_t>>3)&3)*16 + (d&15), elem e = s_t&7.
//     O1/O2/O3 bf16 partials @24/32/40MB; ML fp32 [4][16384][2] @48MB.
// attn_s4: 512 blocks x 256 thr (2 blocks/CU), wave = 32 q-rows (2 strips),
// K LDS-staged (counted vmcnt dbuf), V coalesced direct loads, split-4 KV,
// complement-rank balance, 4-way merge.

#define SEQ 4096
#define DIM 256
#define NBATCH 4
#define KVBLK 64
#define KVT_BYTES 65536

#define QB_OFF   0
#define KV_OFF   (8u*1024*1024)
#define O1_OFF   (24u*1024*1024)
#define O2_OFF   (32u*1024*1024)
#define O3_OFF   (40u*1024*1024)
#define ML_OFF   (48u*1024*1024)
#define WS_NEED  (ML_OFF + 4u*16384*2*4)
// R7 fallback layout
#define ML0_OFF  (32u*1024*1024)
#define ML1_OFF  (ML0_OFF + 16384u*2*4)
#define WS_NEED_FB (ML1_OFF + 16384u*2*4)

typedef __attribute__((ext_vector_type(8))) short bf16x8;
typedef __attribute__((ext_vector_type(4))) float f32x4;
typedef __attribute__((ext_vector_type(4))) unsigned short us4;

static __device__ inline unsigned short f2bf(float f) {
  unsigned int u = __float_as_uint(f);
  u += 0x7FFFu + ((u >> 16) & 1u);
  return (unsigned short)(u >> 16);
}
static __device__ inline float bf2f(unsigned short u) {
  return __uint_as_float(((unsigned int)u) << 16);
}

// ---------------- Kernel 1: QKV projection ----------------
__global__ __launch_bounds__(256) void qkv_gemm(
    const float* __restrict__ x, const float* __restrict__ Wq,
    const float* __restrict__ Wk, const float* __restrict__ Wv,
    unsigned short* __restrict__ qb, char* __restrict__ kv)
{
  __shared__ unsigned short A_lds[128][40];
  __shared__ unsigned short B_lds[64][40];

  const int tid = threadIdx.x;
  const int lane = tid & 63;
  const int w = tid >> 6;
  const int lo = lane & 15, hi = lane >> 4;
  const int mb = blockIdx.x * 128;
  const int nb = blockIdx.y * 64;
  const int z = blockIdx.z;
  const float* Wm = (z == 0) ? Wq : (z == 1) ? Wk : Wv;

  f32x4 acc[2][4];
#pragma unroll
  for (int mi = 0; mi < 2; mi++)
#pragma unroll
    for (int ni = 0; ni < 4; ni++) acc[mi][ni] = (f32x4){0.f, 0.f, 0.f, 0.f};

  for (int ks = 0; ks < 8; ++ks) {
    const int k0 = ks * 32;
    __syncthreads();
#pragma unroll
    for (int i = 0; i < 4; ++i) {
      int f = tid + i * 256;
      int row = f >> 3, c4 = (f & 7) * 4;
      float4 v = *(const float4*)(x + (size_t)(mb + row) * DIM + k0 + c4);
      us4 bv = { f2bf(v.x), f2bf(v.y), f2bf(v.z), f2bf(v.w) };
      *(us4*)&A_lds[row][c4] = bv;
    }
#pragma unroll
    for (int i = 0; i < 2; ++i) {
      int f = tid + i * 256;
      int row = f >> 3, c4 = (f & 7) * 4;
      float4 v = *(const float4*)(Wm + (size_t)(nb + row) * DIM + k0 + c4);
      us4 bv = { f2bf(v.x), f2bf(v.y), f2bf(v.z), f2bf(v.w) };
      *(us4*)&B_lds[row][c4] = bv;
    }
    __syncthreads();
    bf16x8 a[2], bfr[4];
#pragma unroll
    for (int mi = 0; mi < 2; mi++) a[mi] = *(const bf16x8*)&A_lds[w * 32 + mi * 16 + lo][hi * 8];
#pragma unroll
    for (int ni = 0; ni < 4; ni++) bfr[ni] = *(const bf16x8*)&B_lds[ni * 16 + lo][hi * 8];
#pragma unroll
    for (int mi = 0; mi < 2; mi++)
#pragma unroll
      for (int ni = 0; ni < 4; ni++)
        acc[mi][ni] = __builtin_amdgcn_mfma_f32_16x16x32_bf16(a[mi], bfr[ni], acc[mi][ni], 0, 0, 0);
  }

  if (z == 0) {
#pragma unroll
    for (int mi = 0; mi < 2; mi++) {
      int r0 = mb + w * 32 + mi * 16 + hi * 4;
#pragma unroll
      for (int ni = 0; ni < 4; ni++) {
        int col = nb + ni * 16 + lo;
#pragma unroll
        for (int j = 0; j < 4; j++)
          qb[(size_t)(r0 + j) * DIM + col] = f2bf(acc[mi][ni][j]);
      }
    }
  } else if (z == 1) {
    // K: swizzled tile image
#pragma unroll
    for (int mi = 0; mi < 2; mi++) {
      int r0 = mb + w * 32 + mi * 16 + hi * 4;
#pragma unroll
      for (int ni = 0; ni < 4; ni++) {
        int d = nb + ni * 16 + lo;
#pragma unroll
        for (int j = 0; j < 4; j++) {
          int srow = r0 + j;
          int bb = srow >> 12, sl = srow & 4095;
          int t = sl >> 6, r = sl & 63;
          size_t byte = ((size_t)(bb * 64 + t)) * KVT_BYTES +
                        (size_t)((r * 512 + 2 * d) ^ ((r & 7) << 4));
          *(unsigned short*)(kv + byte) = f2bf(acc[mi][ni][j]);
        }
      }
    }
  } else {
    // V: fragment-ordered image (contiguous 1KB per MFMA B-fragment)
#pragma unroll
    for (int mi = 0; mi < 2; mi++) {
      int s0 = mb + w * 32 + mi * 16 + hi * 4;   // j=0 row (global s)
      int bb = s0 >> 12;
      int t = (s0 >> 6) & 63;
      int s_t = s0 & 63;
      int ksI = s_t >> 5;
      int hf = (s_t >> 3) & 3;
      int e0 = s_t & 7;                          // = (hi&1)*4
#pragma unroll
      for (int ni = 0; ni < 4; ni++) {
        int d = nb + ni * 16 + lo;
        int n = d >> 4;
        us4 pv = { f2bf(acc[mi][ni][0]), f2bf(acc[mi][ni][1]),
                   f2bf(acc[mi][ni][2]), f2bf(acc[mi][ni][3]) };
        size_t byte = ((size_t)(bb * 64 + t)) * KVT_BYTES + 32768 +
                      (size_t)(((ksI * 16 + n) << 10) + ((hf * 16 + lo) << 4) + e0 * 2);
        *(us4*)(kv + byte) = pv;
      }
    }
  }
}

// ---------------- Kernel 2a: attn_s4 (split-4, 2-strip waves) ----------------
__global__ __launch_bounds__(256, 2) void attn_s4(
    const unsigned short* __restrict__ qb, const char* __restrict__ kv,
    float* __restrict__ out, unsigned short* __restrict__ op1,
    unsigned short* __restrict__ op2, unsigned short* __restrict__ op3,
    float* __restrict__ ml)
{
  __shared__ char K_lds[2][32768];
  __shared__ unsigned short P_lds[4][16][72];

  const int tid = threadIdx.x;
  const int lane = tid & 63;
  const int w = tid >> 6;
  const int lo = lane & 15, hi = lane >> 4;
  const int id = blockIdx.x;
  const int b = (id & 7) >> 1;
  const int v = ((id >> 3) << 1) | (id & 1);     // 0..127 within batch
  const int r = (v < 64) ? v : 191 - v;          // complement rank pairing
  const int qt = 31 - (r >> 2);                  // 0..31 (QBLK=128)
  const int c = r & 3;                           // chunk 0..3
  const int nt = 2 * qt + 2;
  const int t0 = (nt * c) >> 2;
  const int t1 = (nt * (c + 1)) >> 2;
  const int qbase = qt * 128;
  const float scale = 0.0625f;

  float* mlc = ml + (size_t)c * 16384 * 2;

  if (t0 >= t1) {           // empty chunk: zero-weight partial
    if (lane < 32) {
      int rr = b * SEQ + qbase + w * 32 + lane;
      mlc[(size_t)rr * 2 + 0] = -3e38f;
      mlc[(size_t)rr * 2 + 1] = 0.f;
    }
    return;
  }

  const char* kv_base = kv + (size_t)b * 64 * KVT_BYTES;
  const int rswz = (lo & 7) << 4;

  auto stageK = [&](int t, int buf) {
    const char* src = kv_base + (size_t)t * KVT_BYTES + tid * 16;
    char* dst = &K_lds[buf][0] + tid * 16;
#pragma unroll
    for (int i = 0; i < 8; ++i) {
      __builtin_amdgcn_global_load_lds(
          (const __attribute__((address_space(1))) void*)(src + i * 4096),
          (__attribute__((address_space(3))) void*)(dst + i * 4096),
          16, 0, 0);
    }
  };

  // Q fragments: two 16-row strips per wave
  bf16x8 qf0[8], qf1[8];
  {
    const unsigned short* q0 = qb + (size_t)(b * SEQ + qbase + w * 32 + lo) * DIM;
    const unsigned short* q1 = q0 + (size_t)16 * DIM;
#pragma unroll
    for (int kk = 0; kk < 8; kk++) {
      qf0[kk] = *(const bf16x8*)(q0 + kk * 32 + hi * 8);
      qf1[kk] = *(const bf16x8*)(q1 + kk * 32 + hi * 8);
    }
  }

  stageK(t0, 0);
  if (t0 + 1 < t1) stageK(t0 + 1, 1);

  float m_run[2][4], l_run[2][4];
#pragma unroll
  for (int sp = 0; sp < 2; sp++)
#pragma unroll
    for (int j = 0; j < 4; j++) { m_run[sp][j] = -3e38f; l_run[sp][j] = 0.f; }
  f32x4 oa0[16], oa1[16];
#pragma unroll
  for (int n = 0; n < 16; n++) { oa0[n] = (f32x4){0.f,0.f,0.f,0.f}; oa1[n] = (f32x4){0.f,0.f,0.f,0.f}; }

  for (int t = t0; t < t1; ++t) {
    const int cur = (t - t0) & 1;

    if (t + 1 < t1) {
      asm volatile("s_waitcnt vmcnt(8)" ::: "memory");
    } else {
      asm volatile("s_waitcnt vmcnt(0)" ::: "memory");
    }
    __builtin_amdgcn_sched_barrier(0);
    __builtin_amdgcn_s_barrier();

    // S = Q K^T for both strips (K fragments shared)
    const char* kt = &K_lds[cur][0];
    f32x4 sf0[4], sf1[4];
#pragma unroll
    for (int nf = 0; nf < 4; nf++) {
      f32x4 a0 = (f32x4){0.f,0.f,0.f,0.f}, a1 = (f32x4){0.f,0.f,0.f,0.f};
#pragma unroll
      for (int kk = 0; kk < 8; kk++) {
        int byte_off = (nf * 16 + lo) * 512 + ((kk * 64 + hi * 16) ^ rswz);
        bf16x8 kfr = *(const bf16x8*)(kt + byte_off);
        a0 = __builtin_amdgcn_mfma_f32_16x16x32_bf16(qf0[kk], kfr, a0, 0, 0, 0);
        a1 = __builtin_amdgcn_mfma_f32_16x16x32_bf16(qf1[kk], kfr, a1, 0, 0, 0);
      }
      sf0[nf] = a0; sf1[nf] = a1;
    }

    // scale + causal mask (QBLK=128 > KVBLK=64: diagonal spans tiles nt-2, nt-1)
    const bool diag = (t >= nt - 2);
    float s[2][4][4];
#pragma unroll
    for (int nf = 0; nf < 4; nf++)
#pragma unroll
      for (int j = 0; j < 4; j++) {
        float v0 = sf0[nf][j] * scale;
        float v1 = sf1[nf][j] * scale;
        if (diag) {
          int kg = t * KVBLK + nf * 16 + lo;
          int qg0 = qbase + w * 32 + hi * 4 + j;
          if (kg > qg0) v0 = -__builtin_inff();
          if (kg > qg0 + 16) v1 = -__builtin_inff();
        }
        s[0][nf][j] = v0; s[1][nf][j] = v1;
      }

    // online softmax (defer-max) over both strips
    float vnew[2][4];
#pragma unroll
    for (int sp = 0; sp < 2; sp++)
#pragma unroll
      for (int j = 0; j < 4; j++) {
        float m = fmaxf(fmaxf(s[sp][0][j], s[sp][1][j]), fmaxf(s[sp][2][j], s[sp][3][j]));
        m = fmaxf(m, __shfl_xor(m, 1));
        m = fmaxf(m, __shfl_xor(m, 2));
        m = fmaxf(m, __shfl_xor(m, 4));
        m = fmaxf(m, __shfl_xor(m, 8));
        vnew[sp][j] = m;
      }
    bool grow = false;
#pragma unroll
    for (int sp = 0; sp < 2; sp++)
#pragma unroll
      for (int j = 0; j < 4; j++) grow = grow || (vnew[sp][j] > m_run[sp][j] + 8.f);
    if (__any(grow)) {
#pragma unroll
      for (int j = 0; j < 4; j++) {
        float mn0 = fmaxf(m_run[0][j], vnew[0][j]);
        float mn1 = fmaxf(m_run[1][j], vnew[1][j]);
        float al0 = __expf(m_run[0][j] - mn0);
        float al1 = __expf(m_run[1][j] - mn1);
        m_run[0][j] = mn0; m_run[1][j] = mn1;
        l_run[0][j] *= al0; l_run[1][j] *= al1;
#pragma unroll
        for (int n = 0; n < 16; n++) { oa0[n][j] *= al0; oa1[n][j] *= al1; }
      }
    }
    float pr[2][4][4];
#pragma unroll
    for (int sp = 0; sp < 2; sp++)
#pragma unroll
      for (int j = 0; j < 4; j++) {
        float sum = 0.f;
#pragma unroll
        for (int nf = 0; nf < 4; nf++) {
          pr[sp][nf][j] = __expf(s[sp][nf][j] - m_run[sp][j]);
          sum += pr[sp][nf][j];
        }
        sum += __shfl_xor(sum, 1);
        sum += __shfl_xor(sum, 2);
        sum += __shfl_xor(sum, 4);
        sum += __shfl_xor(sum, 8);
        l_run[sp][j] += sum;
      }

    // P -> per-wave LDS, strip-sequential (buffer reused)
    bf16x8 pas[2][2];
#pragma unroll
    for (int sp = 0; sp < 2; sp++) {
#pragma unroll
      for (int nf = 0; nf < 4; nf++)
#pragma unroll
        for (int j = 0; j < 4; j++)
          P_lds[w][hi * 4 + j][nf * 16 + lo] = f2bf(pr[sp][nf][j]);
      asm volatile("s_waitcnt lgkmcnt(0)" ::: "memory");
      __builtin_amdgcn_sched_barrier(0);
      pas[sp][0] = *(const bf16x8*)&P_lds[w][lo][hi * 8];
      pas[sp][1] = *(const bf16x8*)&P_lds[w][lo][32 + hi * 8];
      asm volatile("s_waitcnt lgkmcnt(0)" ::: "memory");
      __builtin_amdgcn_sched_barrier(0);
    }

    // O += P V: V fragments COALESCED (1KB contiguous per load), shared by strips
    const char* vbase = kv_base + (size_t)t * KVT_BYTES + 32768;
#pragma unroll
    for (int g = 0; g < 4; g++) {
      bf16x8 vf0[4], vf1[4];
#pragma unroll
      for (int k = 0; k < 4; k++) {
        int n = g * 4 + k;
        vf0[k] = *(const bf16x8*)(vbase + (n << 10) + lane * 16);
        vf1[k] = *(const bf16x8*)(vbase + ((16 + n) << 10) + lane * 16);
      }
#pragma unroll
      for (int k = 0; k < 4; k++) {
        int n = g * 4 + k;
        oa0[n] = __builtin_amdgcn_mfma_f32_16x16x32_bf16(pas[0][0], vf0[k], oa0[n], 0, 0, 0);
        oa0[n] = __builtin_amdgcn_mfma_f32_16x16x32_bf16(pas[0][1], vf1[k], oa0[n], 0, 0, 0);
        oa1[n] = __builtin_amdgcn_mfma_f32_16x16x32_bf16(pas[1][0], vf0[k], oa1[n], 0, 0, 0);
        oa1[n] = __builtin_amdgcn_mfma_f32_16x16x32_bf16(pas[1][1], vf1[k], oa1[n], 0, 0, 0);
      }
    }

    __builtin_amdgcn_sched_barrier(0);
    __builtin_amdgcn_s_barrier();
    if (t + 2 < t1) stageK(t + 2, cur);
  }

  // epilogue
  unsigned short* opc = (c == 1) ? op1 : (c == 2) ? op2 : op3;
#pragma unroll
  for (int sp = 0; sp < 2; sp++) {
#pragma unroll
    for (int j = 0; j < 4; j++) {
      int rr = b * SEQ + qbase + w * 32 + sp * 16 + hi * 4 + j;
      float l = l_run[sp][j];
      float inv = (l > 0.f) ? 1.f / l : 0.f;
      if (c == 0) {
        float* orow = out + (size_t)rr * DIM;
#pragma unroll
        for (int n = 0; n < 16; n++) {
          f32x4 o = sp ? oa1[n] : oa0[n];
          orow[n * 16 + lo] = o[j] * inv;
        }
      } else {
        unsigned short* orow = opc + (size_t)rr * DIM;
#pragma unroll
        for (int n = 0; n < 16; n++) {
          f32x4 o = sp ? oa1[n] : oa0[n];
          orow[n * 16 + lo] = f2bf(o[j] * inv);
        }
      }
      if (lo == 0) {
        mlc[(size_t)rr * 2 + 0] = m_run[sp][j];
        mlc[(size_t)rr * 2 + 1] = l;
      }
    }
  }
}

// ---------------- Kernel 2b: 4-way merge ----------------
__global__ __launch_bounds__(256) void merge4(
    const float* __restrict__ ml,
    const unsigned short* __restrict__ op1, const unsigned short* __restrict__ op2,
    const unsigned short* __restrict__ op3, float* __restrict__ out)
{
  int r = blockIdx.x * 4 + (threadIdx.x >> 6);
  int c4 = (threadIdx.x & 63) * 4;
  float m0 = ml[(size_t)r*2], l0 = ml[(size_t)r*2+1];
  float m1 = ml[(size_t)(16384+r)*2], l1 = ml[(size_t)(16384+r)*2+1];
  float m2 = ml[(size_t)(32768+r)*2], l2 = ml[(size_t)(32768+r)*2+1];
  float m3 = ml[(size_t)(49152+r)*2], l3 = ml[(size_t)(49152+r)*2+1];
  float M = fmaxf(fmaxf(m0, m1), fmaxf(m2, m3));
  float w0 = l0 * __expf(m0 - M);
  float w1 = l1 * __expf(m1 - M);
  float w2 = l2 * __expf(m2 - M);
  float w3 = l3 * __expf(m3 - M);
  float inv = 1.f / (w0 + w1 + w2 + w3);
  float4 o0 = *(const float4*)(out + (size_t)r * DIM + c4);
  us4 a = *(const us4*)(op1 + (size_t)r * DIM + c4);
  us4 bq = *(const us4*)(op2 + (size_t)r * DIM + c4);
  us4 cq = *(const us4*)(op3 + (size_t)r * DIM + c4);
  float4 res;
  res.x = (w0*o0.x + w1*bf2f(a.x) + w2*bf2f(bq.x) + w3*bf2f(cq.x)) * inv;
  res.y = (w0*o0.y + w1*bf2f(a.y) + w2*bf2f(bq.y) + w3*bf2f(cq.y)) * inv;
  res.z = (w0*o0.z + w1*bf2f(a.z) + w2*bf2f(bq.z) + w3*bf2f(cq.z)) * inv;
  res.w = (w0*o0.w + w1*bf2f(a.w) + w2*bf2f(bq.w) + w3*bf2f(cq.w)) * inv;
  *(float4*)(out + (size_t)r * DIM + c4) = res;
}

// ---------------- R7 fallback: attn_split (V loads updated to fragment layout) ----------------
__global__ __launch_bounds__(64, 2) void attn_split(
    const unsigned short* __restrict__ qb, const char* __restrict__ kv,
    float* __restrict__ out, unsigned short* __restrict__ o1,
    float* __restrict__ ml0, float* __restrict__ ml1)
{
  __shared__ unsigned short P_lds[16][72];

  const int lane = threadIdx.x & 63;
  const int lo = lane & 15, hi = lane >> 4;
  const int id = blockIdx.x;
  const int x = id & 7;
  const int b = x >> 1;
  const int c = x & 1;
  const int v = id >> 3;
  const int qt = (v & 1) ? (255 - (v >> 1)) : (v >> 1);
  const int nt = (qt >> 2) + 1;
  const int h = (nt + 1) >> 1;
  const int t0 = c ? h : 0;
  const int t1 = c ? nt : h;
  const float scale = 0.0625f;

  const int rbase = b * SEQ + qt * 16;
  if (t0 >= t1) {
    if (lane < 16) {
      ml1[(size_t)(rbase + lane) * 2 + 0] = -1e30f;
      ml1[(size_t)(rbase + lane) * 2 + 1] = 0.f;
    }
    return;
  }

  const char* kv_base = kv + (size_t)b * 64 * KVT_BYTES;
  const int rswz = (lo & 7) << 4;

  bf16x8 qf[8];
  {
    const unsigned short* qrow = qb + (size_t)(rbase + lo) * DIM;
#pragma unroll
    for (int kk = 0; kk < 8; kk++)
      qf[kk] = *(const bf16x8*)(qrow + kk * 32 + hi * 8);
  }

  float m_run[4], l_run[4];
#pragma unroll
  for (int j = 0; j < 4; j++) { m_run[j] = -__builtin_inff(); l_run[j] = 0.f; }
  f32x4 o_acc[16];
#pragma unroll
  for (int n = 0; n < 16; n++) o_acc[n] = (f32x4){0.f, 0.f, 0.f, 0.f};

  for (int t = t0; t < t1; ++t) {
    const char* tileb = kv_base + (size_t)t * KVT_BYTES;

    f32x4 sf[4];
#pragma unroll
    for (int nf = 0; nf < 4; nf++) {
      const char* kbase = tileb + (nf * 16 + lo) * 512;
      bf16x8 kf[8];
#pragma unroll
      for (int kk = 0; kk < 8; kk++)
        kf[kk] = *(const bf16x8*)(kbase + ((kk * 64 + hi * 16) ^ rswz));
      f32x4 a = (f32x4){0.f, 0.f, 0.f, 0.f};
#pragma unroll
      for (int kk = 0; kk < 8; kk++)
        a = __builtin_amdgcn_mfma_f32_16x16x32_bf16(qf[kk], kf[kk], a, 0, 0, 0);
      sf[nf] = a;
    }

    const bool diag = (t == nt - 1);
    float s[4][4];
#pragma unroll
    for (int nf = 0; nf < 4; nf++)
#pragma unroll
      for (int j = 0; j < 4; j++) {
        float vv = sf[nf][j] * scale;
        if (diag) {
          int qg = qt * 16 + hi * 4 + j;
          int kg = t * KVBLK + nf * 16 + lo;
          if (kg > qg) vv = -__builtin_inff();
        }
        s[nf][j] = vv;
      }

    float vnew[4];
#pragma unroll
    for (int j = 0; j < 4; j++) {
      float m = fmaxf(fmaxf(s[0][j], s[1][j]), fmaxf(s[2][j], s[3][j]));
      m = fmaxf(m, __shfl_xor(m, 1));
      m = fmaxf(m, __shfl_xor(m, 2));
      m = fmaxf(m, __shfl_xor(m, 4));
      m = fmaxf(m, __shfl_xor(m, 8));
      vnew[j] = m;
    }
    bool grow = false;
#pragma unroll
    for (int j = 0; j < 4; j++) grow = grow || (vnew[j] > m_run[j] + 8.f);
    if (__any(grow)) {
#pragma unroll
      for (int j = 0; j < 4; j++) {
        float mn = fmaxf(m_run[j], vnew[j]);
        float alpha = __expf(m_run[j] - mn);
        m_run[j] = mn;
        l_run[j] *= alpha;
#pragma unroll
        for (int n = 0; n < 16; n++) o_acc[n][j] *= alpha;
      }
    }
    float pr[4][4];
#pragma unroll
    for (int j = 0; j < 4; j++) {
      float sum = 0.f;
#pragma unroll
      for (int nf = 0; nf < 4; nf++) {
        pr[nf][j] = __expf(s[nf][j] - m_run[j]);
        sum += pr[nf][j];
      }
      sum += __shfl_xor(sum, 1);
      sum += __shfl_xor(sum, 2);
      sum += __shfl_xor(sum, 4);
      sum += __shfl_xor(sum, 8);
      l_run[j] += sum;
    }

#pragma unroll
    for (int nf = 0; nf < 4; nf++)
#pragma unroll
      for (int j = 0; j < 4; j++)
        P_lds[hi * 4 + j][nf * 16 + lo] = f2bf(pr[nf][j]);

    bf16x8 pa0 = *(const bf16x8*)&P_lds[lo][hi * 8];
    bf16x8 pa1 = *(const bf16x8*)&P_lds[lo][32 + hi * 8];

    const char* vglob = tileb + 32768;
#pragma unroll
    for (int g = 0; g < 4; g++) {
      bf16x8 va[4], vb[4];
#pragma unroll
      for (int k = 0; k < 4; k++) {
        int n = g * 4 + k;
        va[k] = *(const bf16x8*)(vglob + (n << 10) + lane * 16);
        vb[k] = *(const bf16x8*)(vglob + ((16 + n) << 10) + lane * 16);
      }
#pragma unroll
      for (int k = 0; k < 4; k++) {
        o_acc[g * 4 + k] = __builtin_amdgcn_mfma_f32_16x16x32_bf16(pa0, va[k], o_acc[g * 4 + k], 0, 0, 0);
        o_acc[g * 4 + k] = __builtin_amdgcn_mfma_f32_16x16x32_bf16(pa1, vb[k], o_acc[g * 4 + k], 0, 0, 0);
      }
    }
  }

  if (c == 0) {
#pragma unroll
    for (int j = 0; j < 4; j++) {
      int r = rbase + hi * 4 + j;
      float inv = 1.f / l_run[j];
      float* orow = out + (size_t)r * DIM;
#pragma unroll
      for (int n = 0; n < 16; n++)
        orow[n * 16 + lo] = o_acc[n][j] * inv;
    }
    if (lo == 0) {
#pragma unroll
      for (int j = 0; j < 4; j++) {
        int r = rbase + hi * 4 + j;
        ml0[(size_t)r * 2 + 0] = m_run[j];
        ml0[(size_t)r * 2 + 1] = l_run[j];
      }
    }
  } else {
#pragma unroll
    for (int j = 0; j < 4; j++) {
      int r = rbase + hi * 4 + j;
      float inv = 1.f / l_run[j];
      unsigned short* orow = o1 + (size_t)r * DIM;
#pragma unroll
      for (int n = 0; n < 16; n++)
        orow[n * 16 + lo] = f2bf(o_acc[n][j] * inv);
    }
    if (lo == 0) {
#pragma unroll
      for (int j = 0; j < 4; j++) {
        int r = rbase + hi * 4 + j;
        ml1[(size_t)r * 2 + 0] = m_run[j];
        ml1[(size_t)r * 2 + 1] = l_run[j];
      }
    }
  }
}

__global__ __launch_bounds__(256) void merge_k(
    const float* __restrict__ ml0, const float* __restrict__ ml1,
    const unsigned short* __restrict__ o1, float* __restrict__ out)
{
  int r = blockIdx.x * 4 + (threadIdx.x >> 6);
  int c4 = (threadIdx.x & 63) * 4;
  float m0 = ml0[(size_t)r * 2 + 0], l0 = ml0[(size_t)r * 2 + 1];
  float m1 = ml1[(size_t)r * 2 + 0], l1 = ml1[(size_t)r * 2 + 1];
  float M = fmaxf(m0, m1);
  float w0 = l0 * __expf(m0 - M);
  float w1 = l1 * __expf(m1 - M);
  float inv = 1.f / (w0 + w1);
  float4 o0 = *(const float4*)(out + (size_t)r * DIM + c4);
  us4 ov = *(const us4*)(o1 + (size_t)r * DIM + c4);
  float4 res;
  res.x = (w0 * o0.x + w1 * bf2f(ov.x)) * inv;
  res.y = (w0 * o0.y + w1 * bf2f(ov.y)) * inv;
  res.z = (w0 * o0.z + w1 * bf2f(ov.z)) * inv;
  res.w = (w0 * o0.w + w1 * bf2f(ov.w)) * inv;
  *(float4*)(out + (size_t)r * DIM + c4) = res;
}

extern "C" void kernel_launch(void* const* d_in, const int* in_sizes, int n_in,
                              void* d_out, int out_size, void* d_ws, size_t ws_size,
                              hipStream_t stream) {
  const float* x  = (const float*)d_in[0];
  const float* Wq = (const float*)d_in[1];
  const float* Wk = (const float*)d_in[2];
  const float* Wv = (const float*)d_in[3];
  char* ws = (char*)d_ws;
  unsigned short* qb = (unsigned short*)(ws + QB_OFF);
  char* kv = ws + KV_OFF;
  float* out = (float*)d_out;

  qkv_gemm<<<dim3(128, 4, 3), 256, 0, stream>>>(x, Wq, Wk, Wv, qb, kv);

  if (ws_size >= (size_t)WS_NEED) {
    unsigned short* op1 = (unsigned short*)(ws + O1_OFF);
    unsigned short* op2 = (unsigned short*)(ws + O2_OFF);
    unsigned short* op3 = (unsigned short*)(ws + O3_OFF);
    float* ml = (float*)(ws + ML_OFF);
    attn_s4<<<dim3(512), 256, 0, stream>>>(qb, kv, out, op1, op2, op3, ml);
    merge4<<<dim3(4096), 256, 0, stream>>>(ml, op1, op2, op3, out);
  } else {
    unsigned short* o1 = (unsigned short*)(ws + O1_OFF);
    float* ml0 = (float*)(ws + ML0_OFF);
    float* ml1 = (float*)(ws + ML1_OFF);
    attn_split<<<dim3(2048), 64, 0, stream>>>(qb, kv, out, o1, ml0, ml1);
    merge_k<<<dim3(4096), 256, 0, stream>>>(ml0, ml1, o1, out);
  }
}

// Round 9
// 191.922 us; speedup vs baseline: 1.3736x; 1.3736x over previous
//
#include <hip/hip_runtime.h>
#include <hip/hip_bf16.h>

// Problem: B=4, S=4096, D=256 single-head causal attention, fp32 in/out.
// ALL tensors in MFMA-fragment order (every attention load = coalesced 1KB):
//  Qf @0:  per 16-row strip s16=row>>4 (global, 0..1023): 8KB =
//          frag kk: byte (s16*8+kk)*1024 + lane*16 + e*2,
//          lane=(hi*16+lo): Q[row16=lo][d=kk*32+hi*8+e]
//  KV @8MB: per (batch, kv-tile t<64) 64KB block:
//   K [0..32K): frag (nf,kk): byte (nf*8+kk)*1024 + lane*16 + e*2,
//          lane=(hi*16+lo): K[s_t=nf*16+lo][d=kk*32+hi*8+e]
//   V [32K..64K): frag (ks,n): byte 32768+(ks*16+n)*1024 + lane*16 + e*2,
//          lane=(hf*16+lo): V[s_t=ks*32+hf*8+e][d=n*16+lo]
//  O1 bf16 @24MB, ml0 @32MB, ml1 @32MB+128KB.
// attn_fd: 2048 one-wave blocks, no barriers/LDS-staging; XCD x serves
// batch x>>1, KV-half x&1 (per-XCD L2 working set ~2MB). Split-2 + merge.

#define SEQ 4096
#define DIM 256
#define NBATCH 4
#define KVBLK 64
#define KVT_BYTES 65536

#define QB_OFF   0
#define KV_OFF   (8u*1024*1024)
#define O1_OFF   (24u*1024*1024)
#define ML0_OFF  (32u*1024*1024)
#define ML1_OFF  (ML0_OFF + 16384u*2*4)

typedef __attribute__((ext_vector_type(8))) short bf16x8;
typedef __attribute__((ext_vector_type(4))) float f32x4;
typedef __attribute__((ext_vector_type(4))) unsigned short us4;

static __device__ inline unsigned short f2bf(float f) {
  unsigned int u = __float_as_uint(f);
  u += 0x7FFFu + ((u >> 16) & 1u);
  return (unsigned short)(u >> 16);
}
static __device__ inline float bf2f(unsigned short u) {
  return __uint_as_float(((unsigned int)u) << 16);
}

// ---------------- Kernel 1: QKV projection, fragment-order epilogues ----------------
__global__ __launch_bounds__(256) void qkv_gemm(
    const float* __restrict__ x, const float* __restrict__ Wq,
    const float* __restrict__ Wk, const float* __restrict__ Wv,
    char* __restrict__ qbf, char* __restrict__ kv)
{
  __shared__ unsigned short A_lds[128][40];
  __shared__ unsigned short B_lds[64][40];

  const int tid = threadIdx.x;
  const int lane = tid & 63;
  const int w = tid >> 6;
  const int lo = lane & 15, hi = lane >> 4;
  const int mb = blockIdx.x * 128;
  const int nb = blockIdx.y * 64;
  const int z = blockIdx.z;
  const float* Wm = (z == 0) ? Wq : (z == 1) ? Wk : Wv;

  f32x4 acc[2][4];
#pragma unroll
  for (int mi = 0; mi < 2; mi++)
#pragma unroll
    for (int ni = 0; ni < 4; ni++) acc[mi][ni] = (f32x4){0.f, 0.f, 0.f, 0.f};

  for (int ks = 0; ks < 8; ++ks) {
    const int k0 = ks * 32;
    __syncthreads();
#pragma unroll
    for (int i = 0; i < 4; ++i) {
      int f = tid + i * 256;
      int row = f >> 3, c4 = (f & 7) * 4;
      float4 v = *(const float4*)(x + (size_t)(mb + row) * DIM + k0 + c4);
      us4 bv = { f2bf(v.x), f2bf(v.y), f2bf(v.z), f2bf(v.w) };
      *(us4*)&A_lds[row][c4] = bv;
    }
#pragma unroll
    for (int i = 0; i < 2; ++i) {
      int f = tid + i * 256;
      int row = f >> 3, c4 = (f & 7) * 4;
      float4 v = *(const float4*)(Wm + (size_t)(nb + row) * DIM + k0 + c4);
      us4 bv = { f2bf(v.x), f2bf(v.y), f2bf(v.z), f2bf(v.w) };
      *(us4*)&B_lds[row][c4] = bv;
    }
    __syncthreads();
    bf16x8 a[2], bfr[4];
#pragma unroll
    for (int mi = 0; mi < 2; mi++) a[mi] = *(const bf16x8*)&A_lds[w * 32 + mi * 16 + lo][hi * 8];
#pragma unroll
    for (int ni = 0; ni < 4; ni++) bfr[ni] = *(const bf16x8*)&B_lds[ni * 16 + lo][hi * 8];
#pragma unroll
    for (int mi = 0; mi < 2; mi++)
#pragma unroll
      for (int ni = 0; ni < 4; ni++)
        acc[mi][ni] = __builtin_amdgcn_mfma_f32_16x16x32_bf16(a[mi], bfr[ni], acc[mi][ni], 0, 0, 0);
  }

  if (z == 0) {
    // Q fragment order
#pragma unroll
    for (int mi = 0; mi < 2; mi++) {
      int r0 = mb + w * 32 + mi * 16 + hi * 4;
#pragma unroll
      for (int ni = 0; ni < 4; ni++) {
        int d = nb + ni * 16 + lo;
        int kkq = d >> 5, hiq = (d >> 3) & 3, eq = d & 7;
#pragma unroll
        for (int j = 0; j < 4; j++) {
          int srow = r0 + j;
          int s16 = srow >> 4, loq = srow & 15;
          size_t byte = ((size_t)(s16 * 8 + kkq) << 10) + ((hiq * 16 + loq) << 4) + eq * 2;
          *(unsigned short*)(qbf + byte) = f2bf(acc[mi][ni][j]);
        }
      }
    }
  } else if (z == 1) {
    // K fragment order
#pragma unroll
    for (int mi = 0; mi < 2; mi++) {
      int r0 = mb + w * 32 + mi * 16 + hi * 4;
#pragma unroll
      for (int ni = 0; ni < 4; ni++) {
        int d = nb + ni * 16 + lo;
        int kkk = d >> 5, hik = (d >> 3) & 3, ek = d & 7;
#pragma unroll
        for (int j = 0; j < 4; j++) {
          int srow = r0 + j;
          int bb = srow >> 12, sl = srow & 4095;
          int t = sl >> 6, r = sl & 63;
          int nf = r >> 4, lok = r & 15;
          size_t byte = ((size_t)(bb * 64 + t)) * KVT_BYTES +
                        ((size_t)(nf * 8 + kkk) << 10) + ((hik * 16 + lok) << 4) + ek * 2;
          *(unsigned short*)(kv + byte) = f2bf(acc[mi][ni][j]);
        }
      }
    }
  } else {
    // V fragment order (8B stores: 4 consecutive s = 4 consecutive e)
#pragma unroll
    for (int mi = 0; mi < 2; mi++) {
      int s0 = mb + w * 32 + mi * 16 + hi * 4;
      int bb = s0 >> 12;
      int t = (s0 >> 6) & 63;
      int s_t = s0 & 63;
      int ksI = s_t >> 5;
      int hf = (s_t >> 3) & 3;
      int e0 = s_t & 7;
#pragma unroll
      for (int ni = 0; ni < 4; ni++) {
        int d = nb + ni * 16 + lo;
        int n = d >> 4;
        us4 pv = { f2bf(acc[mi][ni][0]), f2bf(acc[mi][ni][1]),
                   f2bf(acc[mi][ni][2]), f2bf(acc[mi][ni][3]) };
        size_t byte = ((size_t)(bb * 64 + t)) * KVT_BYTES + 32768 +
                      ((size_t)(ksI * 16 + n) << 10) + ((hf * 16 + lo) << 4) + e0 * 2;
        *(us4*)(kv + byte) = pv;
      }
    }
  }
}

// ---------------- Kernel 2a: flash-decoding attention (split-2, all-coalesced) ----------------
// 2048 blocks x 64 thr. x=id&7: batch=x>>1, chunk=x&1 (XCD-bound KV half).
// v=id>>3: qt = (v&1)? 255-(v>>1) : v>>1 (heavy/light alternation per XCD).
__global__ __launch_bounds__(64, 2) void attn_fd(
    const char* __restrict__ qbf, const char* __restrict__ kv,
    float* __restrict__ out, unsigned short* __restrict__ o1,
    float* __restrict__ ml0, float* __restrict__ ml1)
{
  __shared__ unsigned short P_lds[16][72];

  const int lane = threadIdx.x & 63;
  const int lo = lane & 15, hi = lane >> 4;
  const int id = blockIdx.x;
  const int x = id & 7;
  const int b = x >> 1;
  const int c = x & 1;
  const int v = id >> 3;
  const int qt = (v & 1) ? (255 - (v >> 1)) : (v >> 1);
  const int nt = (qt >> 2) + 1;
  const int h = (nt + 1) >> 1;
  const int t0 = c ? h : 0;
  const int t1 = c ? nt : h;
  const float scale = 0.0625f;
  const int rbase = b * SEQ + qt * 16;

  if (t0 >= t1) {
    if (lane < 16) {
      ml1[(size_t)(rbase + lane) * 2 + 0] = -1e30f;
      ml1[(size_t)(rbase + lane) * 2 + 1] = 0.f;
    }
    return;
  }

  const char* kv_base = kv + (size_t)b * 64 * KVT_BYTES;

  // Q fragments: 8 coalesced 1KB loads
  bf16x8 qf[8];
  {
    const char* qp = qbf + ((size_t)(b * 256 + qt) << 13) + lane * 16;
#pragma unroll
    for (int kk = 0; kk < 8; kk++)
      qf[kk] = *(const bf16x8*)(qp + kk * 1024);
  }

  float m_run[4], l_run[4];
#pragma unroll
  for (int j = 0; j < 4; j++) { m_run[j] = -__builtin_inff(); l_run[j] = 0.f; }
  f32x4 o_acc[16];
#pragma unroll
  for (int n = 0; n < 16; n++) o_acc[n] = (f32x4){0.f, 0.f, 0.f, 0.f};

  for (int t = t0; t < t1; ++t) {
    const char* tileb = kv_base + (size_t)t * KVT_BYTES;
    const char* kfb = tileb + lane * 16;

    // S = Q K^T; K frags coalesced, double-buffered across nf groups
    bf16x8 kf[2][8];
#pragma unroll
    for (int kk = 0; kk < 8; kk++)
      kf[0][kk] = *(const bf16x8*)(kfb + kk * 1024);

    f32x4 sf[4];
#pragma unroll
    for (int nf = 0; nf < 4; nf++) {
      if (nf < 3) {
#pragma unroll
        for (int kk = 0; kk < 8; kk++)
          kf[(nf + 1) & 1][kk] = *(const bf16x8*)(kfb + ((nf + 1) * 8 + kk) * 1024);
      }
      f32x4 a = (f32x4){0.f, 0.f, 0.f, 0.f};
#pragma unroll
      for (int kk = 0; kk < 8; kk++)
        a = __builtin_amdgcn_mfma_f32_16x16x32_bf16(qf[kk], kf[nf & 1][kk], a, 0, 0, 0);
      sf[nf] = a;
    }

    const bool diag = (t == nt - 1);
    float s[4][4];
#pragma unroll
    for (int nf = 0; nf < 4; nf++)
#pragma unroll
      for (int j = 0; j < 4; j++) {
        float vv = sf[nf][j] * scale;
        if (diag) {
          int qg = qt * 16 + hi * 4 + j;
          int kg = t * KVBLK + nf * 16 + lo;
          if (kg > qg) vv = -__builtin_inff();
        }
        s[nf][j] = vv;
      }

    // online softmax with defer-max
    float vnew[4];
#pragma unroll
    for (int j = 0; j < 4; j++) {
      float m = fmaxf(fmaxf(s[0][j], s[1][j]), fmaxf(s[2][j], s[3][j]));
      m = fmaxf(m, __shfl_xor(m, 1));
      m = fmaxf(m, __shfl_xor(m, 2));
      m = fmaxf(m, __shfl_xor(m, 4));
      m = fmaxf(m, __shfl_xor(m, 8));
      vnew[j] = m;
    }
    bool grow = false;
#pragma unroll
    for (int j = 0; j < 4; j++) grow = grow || (vnew[j] > m_run[j] + 8.f);
    if (__any(grow)) {
#pragma unroll
      for (int j = 0; j < 4; j++) {
        float mn = fmaxf(m_run[j], vnew[j]);
        float alpha = __expf(m_run[j] - mn);
        m_run[j] = mn;
        l_run[j] *= alpha;
#pragma unroll
        for (int n = 0; n < 16; n++) o_acc[n][j] *= alpha;
      }
    }
    float pr[4][4];
#pragma unroll
    for (int j = 0; j < 4; j++) {
      float sum = 0.f;
#pragma unroll
      for (int nf = 0; nf < 4; nf++) {
        pr[nf][j] = __expf(s[nf][j] - m_run[j]);
        sum += pr[nf][j];
      }
      sum += __shfl_xor(sum, 1);
      sum += __shfl_xor(sum, 2);
      sum += __shfl_xor(sum, 4);
      sum += __shfl_xor(sum, 8);
      l_run[j] += sum;
    }

    // P -> LDS roundtrip (wave-local)
#pragma unroll
    for (int nf = 0; nf < 4; nf++)
#pragma unroll
      for (int j = 0; j < 4; j++)
        P_lds[hi * 4 + j][nf * 16 + lo] = f2bf(pr[nf][j]);
    asm volatile("s_waitcnt lgkmcnt(0)" ::: "memory");
    __builtin_amdgcn_sched_barrier(0);
    bf16x8 pa0 = *(const bf16x8*)&P_lds[lo][hi * 8];
    bf16x8 pa1 = *(const bf16x8*)&P_lds[lo][32 + hi * 8];
    asm volatile("s_waitcnt lgkmcnt(0)" ::: "memory");
    __builtin_amdgcn_sched_barrier(0);

    // O += P V; V frags coalesced 1KB
    const char* vglob = tileb + 32768 + lane * 16;
#pragma unroll
    for (int g = 0; g < 4; g++) {
      bf16x8 va[4], vb[4];
#pragma unroll
      for (int k = 0; k < 4; k++) {
        int n = g * 4 + k;
        va[k] = *(const bf16x8*)(vglob + (n << 10));
        vb[k] = *(const bf16x8*)(vglob + ((16 + n) << 10));
      }
#pragma unroll
      for (int k = 0; k < 4; k++) {
        o_acc[g * 4 + k] = __builtin_amdgcn_mfma_f32_16x16x32_bf16(pa0, va[k], o_acc[g * 4 + k], 0, 0, 0);
        o_acc[g * 4 + k] = __builtin_amdgcn_mfma_f32_16x16x32_bf16(pa1, vb[k], o_acc[g * 4 + k], 0, 0, 0);
      }
    }
  }

  // epilogue: chunk0 -> out + ml0 ; chunk1 -> bf16 partial + ml1
  if (c == 0) {
#pragma unroll
    for (int j = 0; j < 4; j++) {
      int r = rbase + hi * 4 + j;
      float inv = 1.f / l_run[j];
      float* orow = out + (size_t)r * DIM;
#pragma unroll
      for (int n = 0; n < 16; n++)
        orow[n * 16 + lo] = o_acc[n][j] * inv;
    }
    if (lo == 0) {
#pragma unroll
      for (int j = 0; j < 4; j++) {
        int r = rbase + hi * 4 + j;
        ml0[(size_t)r * 2 + 0] = m_run[j];
        ml0[(size_t)r * 2 + 1] = l_run[j];
      }
    }
  } else {
#pragma unroll
    for (int j = 0; j < 4; j++) {
      int r = rbase + hi * 4 + j;
      float inv = 1.f / l_run[j];
      unsigned short* orow = o1 + (size_t)r * DIM;
#pragma unroll
      for (int n = 0; n < 16; n++)
        orow[n * 16 + lo] = f2bf(o_acc[n][j] * inv);
    }
    if (lo == 0) {
#pragma unroll
      for (int j = 0; j < 4; j++) {
        int r = rbase + hi * 4 + j;
        ml1[(size_t)r * 2 + 0] = m_run[j];
        ml1[(size_t)r * 2 + 1] = l_run[j];
      }
    }
  }
}

// ---------------- Kernel 2b: merge partials ----------------
__global__ __launch_bounds__(256) void merge_k(
    const float* __restrict__ ml0, const float* __restrict__ ml1,
    const unsigned short* __restrict__ o1, float* __restrict__ out)
{
  int r = blockIdx.x * 4 + (threadIdx.x >> 6);
  int c4 = (threadIdx.x & 63) * 4;
  float m0 = ml0[(size_t)r * 2 + 0], l0 = ml0[(size_t)r * 2 + 1];
  float m1 = ml1[(size_t)r * 2 + 0], l1 = ml1[(size_t)r * 2 + 1];
  float M = fmaxf(m0, m1);
  float w0 = l0 * __expf(m0 - M);
  float w1 = l1 * __expf(m1 - M);
  float inv = 1.f / (w0 + w1);
  float4 o0 = *(const float4*)(out + (size_t)r * DIM + c4);
  us4 ov = *(const us4*)(o1 + (size_t)r * DIM + c4);
  float4 res;
  res.x = (w0 * o0.x + w1 * bf2f(ov.x)) * inv;
  res.y = (w0 * o0.y + w1 * bf2f(ov.y)) * inv;
  res.z = (w0 * o0.z + w1 * bf2f(ov.z)) * inv;
  res.w = (w0 * o0.w + w1 * bf2f(ov.w)) * inv;
  *(float4*)(out + (size_t)r * DIM + c4) = res;
}

extern "C" void kernel_launch(void* const* d_in, const int* in_sizes, int n_in,
                              void* d_out, int out_size, void* d_ws, size_t ws_size,
                              hipStream_t stream) {
  const float* x  = (const float*)d_in[0];
  const float* Wq = (const float*)d_in[1];
  const float* Wk = (const float*)d_in[2];
  const float* Wv = (const float*)d_in[3];
  char* ws = (char*)d_ws;
  char* qbf = ws + QB_OFF;
  char* kv  = ws + KV_OFF;
  unsigned short* o1 = (unsigned short*)(ws + O1_OFF);
  float* ml0 = (float*)(ws + ML0_OFF);
  float* ml1 = (float*)(ws + ML1_OFF);
  float* out = (float*)d_out;

  qkv_gemm<<<dim3(128, 4, 3), 256, 0, stream>>>(x, Wq, Wk, Wv, qbf, kv);
  attn_fd<<<dim3(2048), 64, 0, stream>>>(qbf, kv, out, o1, ml0, ml1);
  merge_k<<<dim3(4096), 256, 0, stream>>>(ml0, ml1, o1, out);
}